// Round 2
// baseline (178.091 us; speedup 1.0000x reference)
//
#include <hip/hip_runtime.h>

#define Bn 256
#define Ln 512
#define Tn 32
#define START_S 30
#define STOP_S 31

// DPP row_ror:k within 16-lane rows (VALU-speed cross-lane)
#define DPP_ROR_F(v, k) __int_as_float(__builtin_amdgcn_update_dpp(0, __float_as_int(v), 0x120|(k), 0xF, 0xF, true))
// ds_swizzle bit-mode, imm pattern (no address VGPR)
#define SWZ_F(v, pat)   __int_as_float(__builtin_amdgcn_ds_swizzle(__float_as_int(v), (pat)))

__global__ __launch_bounds__(64) void crf_nll_kernel(
    const float* __restrict__ feats,
    const unsigned char* __restrict__ maskb,
    const int* __restrict__ tags,
    const float* __restrict__ trans,
    float* __restrict__ out)
{
    const int lane = threadIdx.x;
    const int j    = lane & 31;          // state id
    const int j16  = j ^ 16;
    const int b    = blockIdx.x * 2 + (lane >> 5);   // 2 batch rows per wave

    const float* frow = feats + (size_t)b * Ln * Tn;
    const int*   trow = tags  + (size_t)b * Ln;

    // ---- per-row length (mask layout probe: bool(1B) vs int32) ----
    const bool boolLayout = (maskb[1] != 0);
    int cnt = 0;
    if (boolLayout) {
        const unsigned char* mrow = maskb + (size_t)b * Ln;
        #pragma unroll
        for (int it = 0; it < 16; ++it) cnt += (mrow[it*32 + j] != 0) ? 1 : 0;
    } else {
        const int* mrow = (const int*)maskb + (size_t)b * Ln;
        #pragma unroll
        for (int it = 0; it < 16; ++it) cnt += (mrow[it*32 + j] != 0) ? 1 : 0;
    }
    cnt += __shfl_xor(cnt, 1); cnt += __shfl_xor(cnt, 2);
    cnt += __shfl_xor(cnt, 4); cnt += __shfl_xor(cnt, 8);
    cnt += __shfl_xor(cnt, 16);
    const int len = cnt;                 // same in all 32 lanes of the half-wave

    // ---- gold score (per half-wave row) ----
    float g = 0.f;
    #pragma unroll
    for (int it = 0; it < 16; ++it) {
        int l = it*32 + j;
        if (l < len) {
            int tc = trow[l];
            int tp = (l == 0) ? START_S : trow[l-1];
            g += frow[(size_t)l*Tn + tc] + trans[tp*Tn + tc];
        }
    }
    if (j == 0) g += trans[trow[len-1]*Tn + STOP_S];   // end energy
    g += __shfl_xor(g, 1); g += __shfl_xor(g, 2);
    g += __shfl_xor(g, 4); g += __shfl_xor(g, 8);
    g += __shfl_xor(g, 16);

    // ---- weights w[i][j] = exp(trans[i][j]); self-calibrated DPP source map ----
    float w_own[16], w_oth[16];
    w_own[0] = __expf(trans[j*Tn + j]);
    w_oth[0] = __expf(trans[j16*Tn + j]);
#define CALW(k) { int so = __builtin_amdgcn_update_dpp(0, j,   0x120|(k), 0xF, 0xF, true); \
                  int st = __builtin_amdgcn_update_dpp(0, j16, 0x120|(k), 0xF, 0xF, true); \
                  w_own[k] = __expf(trans[so*Tn + j]); \
                  w_oth[k] = __expf(trans[st*Tn + j]); }
    CALW(1) CALW(2) CALW(3) CALW(4) CALW(5) CALW(6) CALW(7)
    CALW(8) CALW(9) CALW(10) CALW(11) CALW(12) CALW(13) CALW(14) CALW(15)
#undef CALW

    // ---- linear-space forward recursion ----
    float P = __expf(frow[j] + trans[START_S*Tn + j]);   // scaled partition, M = log-scale
    float M = 0.f;
    float fr1 = frow[Tn + j];        // raw feats for l=1
    float fr2 = frow[2*Tn + j];      // raw feats for l=2 (2-deep prefetch)
    float bcv = 1.f;                 // P[1] broadcast for rescale

    #pragma unroll 8
    for (int l = 1; l < Ln; ++l) {
        float Fl = __expf(fr1);                   // off-chain: computed from 2-iter-old load
        fr1 = fr2;
        int ln = (l + 2 < Ln) ? (l + 2) : (Ln - 1);
        fr2 = frow[(size_t)ln*Tn + j];

        bool act = (l < len);
        if ((l & 7) == 0) {                       // uniform branch: rescale, folded into F
            float inv = 1.0f / bcv;
            Fl *= inv;
            float dM = __logf(bcv);
            M = act ? (M + dM) : M;
        }

        float sw = SWZ_F(P, 0x401F);              // lane^16: other 16-group (issued first)
        float a0 = P * w_own[0];
        float a1 = DPP_ROR_F(P,1) * w_own[1];
        float a2 = DPP_ROR_F(P,2) * w_own[2];
        float a3 = DPP_ROR_F(P,3) * w_own[3];
#define OWNT(k, acc) acc = fmaf(DPP_ROR_F(P,k), w_own[k], acc);
        OWNT(4,a0)  OWNT(5,a1)  OWNT(6,a2)  OWNT(7,a3)
        OWNT(8,a0)  OWNT(9,a1)  OWNT(10,a2) OWNT(11,a3)
        OWNT(12,a0) OWNT(13,a1) OWNT(14,a2) OWNT(15,a3)
#undef OWNT
        a0 = fmaf(sw, w_oth[0], a0);
#define OTHT(k, acc) acc = fmaf(DPP_ROR_F(sw,k), w_oth[k], acc);
        OTHT(1,a1)  OTHT(2,a2)  OTHT(3,a3)
        OTHT(4,a0)  OTHT(5,a1)  OTHT(6,a2)  OTHT(7,a3)
        OTHT(8,a0)  OTHT(9,a1)  OTHT(10,a2) OTHT(11,a3)
        OTHT(12,a0) OTHT(13,a1) OTHT(14,a2) OTHT(15,a3)
#undef OTHT
        float s  = (a0 + a1) + (a2 + a3);
        float pn = s * Fl;
        P = act ? pn : P;                         // mask: freeze past sequence end
        if ((l & 7) == 7) bcv = SWZ_F(P, 0x20);   // broadcast P[1] for next rescale
    }

    // ---- final LSE into STOP ----
    float x = P * __expf(trans[j*Tn + STOP_S]);
    x += __shfl_xor(x, 1); x += __shfl_xor(x, 2);
    x += __shfl_xor(x, 4); x += __shfl_xor(x, 8);
    x += __shfl_xor(x, 16);
    float fwd = M + __logf(x);

    float tot = fwd - g;                          // valid in all lanes
    float other = __shfl(tot, 32);                // row B's total (shfl outside divergence)
    if (lane == 0) atomicAdd(out, tot + other);
}

extern "C" void kernel_launch(void* const* d_in, const int* in_sizes, int n_in,
                              void* d_out, int out_size, void* d_ws, size_t ws_size,
                              hipStream_t stream) {
    const float* feats = (const float*)d_in[0];
    const unsigned char* maskb = (const unsigned char*)d_in[1];
    const int* tags = (const int*)d_in[2];
    const float* trans = (const float*)d_in[3];
    float* out = (float*)d_out;

    hipMemsetAsync(out, 0, sizeof(float), stream);
    crf_nll_kernel<<<Bn/2, 64, 0, stream>>>(feats, maskb, tags, trans, out);
}